// Round 6
// baseline (523.109 us; speedup 1.0000x reference)
//
#include <hip/hip_runtime.h>

// Viterbi CRF decode: potentials [B,T,C] f32, transitions [C,C] f32 -> one-hot [B,T,C] f32
// B=256, T=1024, C=128.
//
// crf_fwd : max-only DP (no argmax). Stashes q_t = max_p(alpha_{t-1}[p]+T[p][c])
//           (PRE-pot max) rows into d_out as scratch; row 0 = zeros. LDS alpha
//           double-buffer carries alpha_t = q_t + pot_t.
//           r6 KEY fix: no lambda, no local arrays. The old [&]-lambda STEP took
//           addresses of tr/pc arrays; each step's asm "memory" barrier then
//           forced them to scratch + per-step reloads (VGPR_Count=40 proved it),
//           dragging store latency into the serial chain (~1000 cyc/step floor
//           across r2-r5). Now: 16 named f32x2 trans regs, named pc/pn/q scalars,
//           q flushed to global once per 8-step group -> steps are pure LDS/VALU.
// crf_bwd : per step t: M = q_t[tag] (exact max via readlane) -> backpointer =
//           first p with (q_{t-1}[p]+pot_{t-1}[p]) + T[p][tag] == M (bit-exact
//           replay of fwd's adds) -> ballot+ffs. No max-reduce in the chain.

typedef float f32x2 __attribute__((ext_vector_type(2)));

constexpr int NB = 256;
constexpr int NT = 1024;
constexpr int NC = 128;

template <int CTRL>
__device__ __forceinline__ float dpp_mov(float v) {
  return __int_as_float(__builtin_amdgcn_update_dpp(
      __float_as_int(v), __float_as_int(v), CTRL, 0xF, 0xF, false));
}
template <int CTRL>
__device__ __forceinline__ float fmax_dpp(float v) {
  return fmaxf(v, dpp_mov<CTRL>(v));
}
__device__ __forceinline__ float wave_max_to_lane63(float m) {
  m = fmax_dpp<0x111>(m);  // row_shr:1
  m = fmax_dpp<0x112>(m);  // row_shr:2
  m = fmax_dpp<0x114>(m);  // row_shr:4
  m = fmax_dpp<0x118>(m);  // row_shr:8
  m = fmax_dpp<0x142>(m);  // row_bcast:15
  m = fmax_dpp<0x143>(m);  // row_bcast:31 -> lane63 has full max
  return m;
}

// ---------------- forward ----------------
// alpha LDS layout: p stored at 12*(p>>3) + (p&7); chunk i at floats 12i..12i+7.

constexpr int ABUF = 192;  // padded floats per buffer (16 chunks * 12)

// named trans pair with one-time VGPR pin (components -> no address ever taken)
#define MKT(T, EA, EB)                                        \
  f32x2 T;                                                    \
  {                                                           \
    float _x = (EA), _y = (EB);                               \
    asm volatile("" : "+v"(_x), "+v"(_y));                    \
    T = f32x2{_x, _y};                                        \
  }

#define TREE8(P0, P1, P2, P3)                                               \
  fmaxf(fmaxf(fmaxf((P0).x, (P0).y), fmaxf((P1).x, (P1).y)),                \
        fmaxf(fmaxf((P2).x, (P2).y), fmaxf((P3).x, (P3).y)))

#define STEP(QACC, PCJ, CUR)                                                 \
  do {                                                                       \
    const float4* _af = (CUR) ? afB : afA;                                   \
    float4 _a0 = _af[0];                                                     \
    float4 _a1 = _af[1];                                                     \
    f32x2 _av0 = f32x2{_a0.x, _a0.y};                                        \
    f32x2 _av1 = f32x2{_a0.z, _a0.w};                                        \
    f32x2 _av2 = f32x2{_a1.x, _a1.y};                                        \
    f32x2 _av3 = f32x2{_a1.z, _a1.w};                                        \
    f32x2 _p0 = _av0 + T00, _p1 = _av1 + T10, _p2 = _av2 + T20,              \
          _p3 = _av3 + T30;                                                  \
    float _mj0 = TREE8(_p0, _p1, _p2, _p3);                                  \
    _p0 = _av0 + T01; _p1 = _av1 + T11; _p2 = _av2 + T21; _p3 = _av3 + T31;  \
    float _mj1 = TREE8(_p0, _p1, _p2, _p3);                                  \
    _p0 = _av0 + T02; _p1 = _av1 + T12; _p2 = _av2 + T22; _p3 = _av3 + T32;  \
    float _mj2 = TREE8(_p0, _p1, _p2, _p3);                                  \
    _p0 = _av0 + T03; _p1 = _av1 + T13; _p2 = _av2 + T23; _p3 = _av3 + T33;  \
    float _mj3 = TREE8(_p0, _p1, _p2, _p3);                                  \
    float _d0 = dpp_mov<0xB1>(_mj0);                                         \
    float _d1 = dpp_mov<0xB1>(_mj1);                                         \
    float _d2 = dpp_mov<0xB1>(_mj2);                                         \
    float _d3 = dpp_mov<0xB1>(_mj3);                                         \
    float _r0 = fmaxf(b0 ? _mj2 : _mj0, b0 ? _d2 : _d0);                     \
    float _r1 = fmaxf(b0 ? _mj3 : _mj1, b0 ? _d3 : _d1);                     \
    float _u0 = dpp_mov<0x4E>(_r0);                                          \
    float _u1 = dpp_mov<0x4E>(_r1);                                          \
    float _q = fmaxf(b1 ? _r1 : _r0, b1 ? _u1 : _u0);                        \
    _q = fmaxf(_q, dpp_mov<0x114>(_q));                                      \
    _q = fmaxf(_q, dpp_mov<0x118>(_q));                                      \
    if (wr) {                                                                \
      alpha[((CUR) ^ 1) * ABUF + widx] = _q + (PCJ);                         \
      (QACC) = _q;                                                           \
    }                                                                        \
    asm volatile("s_waitcnt lgkmcnt(0)\n\ts_barrier" ::: "memory");          \
  } while (0)

#define PREF(PNJ, J)                                                         \
  {                                                                          \
    int _row = 9 + 8 * grp + (J);                                            \
    if (_row > NT - 1) _row = NT - 1;                                        \
    PNJ = potb[(size_t)_row * NC + cw];                                      \
  }

__global__ __launch_bounds__(512, 2)
void crf_fwd(const float* __restrict__ pot, const float* __restrict__ trans,
             float* __restrict__ out) {
  __shared__ __align__(16) float alpha[2 * ABUF];

  const int tid = threadIdx.x;
  const int b = blockIdx.x;
  const int w = tid >> 6;          // wave 0..7
  const int l = tid & 63;          // lane
  const int r = l >> 4;            // row 0..3
  const int i = l & 15;            // p-chunk
  const int g = w * 4 + r;         // c-quad 0..31
  const bool b0 = (l & 1) != 0;
  const bool b1 = (l & 2) != 0;
  const bool wr = (i >= 12);       // writer lanes: one per c in the quad
  const int cw = 4 * g + 2 * (i & 1) + ((i >> 1) & 1);   // writer's c
  const int widx = 12 * (cw >> 3) + (cw & 7);            // writer's padded LDS index

  const float* potb = pot + (size_t)b * NT * NC;
  float* outb = out + (size_t)b * NT * NC;

  // ---- transitions into 16 NAMED f32x2 regs: Tkj = (T[8i+2k][4g+j], T[8i+2k+1][4g+j])
  const float* tb = trans + (8 * i) * NC + 4 * g;
  float4 L0 = *(const float4*)(tb + 0 * NC);
  float4 L1 = *(const float4*)(tb + 1 * NC);
  float4 L2 = *(const float4*)(tb + 2 * NC);
  float4 L3 = *(const float4*)(tb + 3 * NC);
  float4 L4 = *(const float4*)(tb + 4 * NC);
  float4 L5 = *(const float4*)(tb + 5 * NC);
  float4 L6 = *(const float4*)(tb + 6 * NC);
  float4 L7 = *(const float4*)(tb + 7 * NC);
  MKT(T00, L0.x, L1.x) MKT(T01, L0.y, L1.y) MKT(T02, L0.z, L1.z) MKT(T03, L0.w, L1.w)
  MKT(T10, L2.x, L3.x) MKT(T11, L2.y, L3.y) MKT(T12, L2.z, L3.z) MKT(T13, L2.w, L3.w)
  MKT(T20, L4.x, L5.x) MKT(T21, L4.y, L5.y) MKT(T22, L4.z, L5.z) MKT(T23, L4.w, L5.w)
  MKT(T30, L6.x, L7.x) MKT(T31, L6.y, L7.y) MKT(T32, L6.z, L7.z) MKT(T33, L6.w, L7.w)

  // named pot prefetch + q accumulators (writer lanes only)
  float pc0, pc1, pc2, pc3, pc4, pc5, pc6, pc7;
  float pn0, pn1, pn2, pn3, pn4, pn5, pn6, pn7;
  float q0, q1, q2, q3, q4, q5, q6, q7;

  if (wr) {
    alpha[widx] = potb[cw];                  // alpha_0 = pot[:,0,:]
    outb[cw] = 0.0f;                         // q_0 := 0  (alpha_0 = 0 + pot_0)
    pc0 = potb[1 * NC + cw]; pc1 = potb[2 * NC + cw];
    pc2 = potb[3 * NC + cw]; pc3 = potb[4 * NC + cw];
    pc4 = potb[5 * NC + cw]; pc5 = potb[6 * NC + cw];
    pc6 = potb[7 * NC + cw]; pc7 = potb[8 * NC + cw];
  }
  asm volatile("s_waitcnt lgkmcnt(0)\n\ts_barrier" ::: "memory");

  const float4* afA = (const float4*)(alpha) + 3 * i;
  const float4* afB = (const float4*)(alpha + ABUF) + 3 * i;

  for (int grp = 0; grp < 127; ++grp) {
    if (wr) {
      if (grp > 0) {  // flush previous group's q (fire-and-forget, outside steps)
        float* fo = outb + (size_t)(8 * grp - 7) * NC + cw;
        fo[0 * NC] = q0; fo[1 * NC] = q1; fo[2 * NC] = q2; fo[3 * NC] = q3;
        fo[4 * NC] = q4; fo[5 * NC] = q5; fo[6 * NC] = q6; fo[7 * NC] = q7;
      }
      PREF(pn0, 0) PREF(pn1, 1) PREF(pn2, 2) PREF(pn3, 3)
      PREF(pn4, 4) PREF(pn5, 5) PREF(pn6, 6) PREF(pn7, 7)
    }
    STEP(q0, pc0, 0); STEP(q1, pc1, 1); STEP(q2, pc2, 0); STEP(q3, pc3, 1);
    STEP(q4, pc4, 0); STEP(q5, pc5, 1); STEP(q6, pc6, 0); STEP(q7, pc7, 1);
    pc0 = pn0; pc1 = pn1; pc2 = pn2; pc3 = pn3;
    pc4 = pn4; pc5 = pn5; pc6 = pn6; pc7 = pn7;
  }
  if (wr) {  // flush group 126 (t = 1009..1016)
    float* fo = outb + (size_t)1009 * NC + cw;
    fo[0 * NC] = q0; fo[1 * NC] = q1; fo[2 * NC] = q2; fo[3 * NC] = q3;
    fo[4 * NC] = q4; fo[5 * NC] = q5; fo[6 * NC] = q6; fo[7 * NC] = q7;
  }
  // tail t = 1017..1023
  STEP(q0, pc0, 0); STEP(q1, pc1, 1); STEP(q2, pc2, 0); STEP(q3, pc3, 1);
  STEP(q4, pc4, 0); STEP(q5, pc5, 1); STEP(q6, pc6, 0);
  if (wr) {
    float* fo = outb + (size_t)1017 * NC + cw;
    fo[0 * NC] = q0; fo[1 * NC] = q1; fo[2 * NC] = q2; fo[3 * NC] = q3;
    fo[4 * NC] = q4; fo[5 * NC] = q5; fo[6 * NC] = q6;
  }
}

// ---------------- backward ----------------
// tTp[c][l] = (T[l][c], T[64+l][c]) as float2 in LDS (64 KiB).
// Wave 0 chases; per step only an equality scan against M = q_t[tag].

__global__ __launch_bounds__(256)
void crf_bwd(const float* __restrict__ pot, const float* __restrict__ trans,
             float* __restrict__ out) {
  extern __shared__ float tTf[];   // float2[NC][64] interleaved
  const int tid = threadIdx.x;
  const int b = blockIdx.x;
  const float* potb = pot + (size_t)b * NT * NC;
  float* outb = out + (size_t)b * NT * NC;

  {
    const int rr = tid >> 1;   // source row p of trans
    const int h = tid & 1;     // which half of the row
    const float4* src = (const float4*)(trans + rr * NC + h * 64);
    const int lo = rr & 63, hb = rr >> 6;
    #pragma unroll
    for (int j = 0; j < 16; ++j) {
      float4 q = src[j];
      int cb = h * 64 + 4 * j;
      tTf[(cb + 0) * 128 + lo * 2 + hb] = q.x;
      tTf[(cb + 1) * 128 + lo * 2 + hb] = q.y;
      tTf[(cb + 2) * 128 + lo * 2 + hb] = q.z;
      tTf[(cb + 3) * 128 + lo * 2 + hb] = q.w;
    }
  }
  __syncthreads();
  if (tid >= 64) return;
  const int l = tid;
  const f32x2* tTp = (const f32x2*)tTf;

  // ---- init at t = NT-1: alpha_last = q_last + pot_last; full argmax (once) ----
  float qlo_t = outb[(NT - 1) * NC + l];
  float qhi_t = outb[(NT - 1) * NC + 64 + l];
  float alo_t = qlo_t + potb[(NT - 1) * NC + l];
  float ahi_t = qhi_t + potb[(NT - 1) * NC + 64 + l];
  float m0 = wave_max_to_lane63(fmaxf(alo_t, ahi_t));
  float M0 = __int_as_float(__builtin_amdgcn_readlane(__float_as_int(m0), 63));
  unsigned long long bl = __ballot(alo_t == M0);
  unsigned long long bh = __ballot(ahi_t == M0);
  int tag = bl ? (__ffsll((long long)bl) - 1)
               : (64 + __ffsll((long long)bh) - 1);

  // ---- prefetch rows 1022..1015 (q and pot), precompute alpha ----
  float cqlo[8], cqhi[8], calo[8], cahi[8];
  float nqlo[8], nqhi[8], nplo[8], nphi[8];
  #pragma unroll
  for (int j = 0; j < 8; ++j) {
    int rw = NT - 2 - j;
    cqlo[j] = outb[rw * NC + l];
    cqhi[j] = outb[rw * NC + 64 + l];
    calo[j] = cqlo[j] + potb[rw * NC + l];
    cahi[j] = cqhi[j] + potb[rw * NC + 64 + l];
  }

  for (int g = 0; g < 128; ++g) {
    #pragma unroll
    for (int j = 0; j < 8; ++j) {      // prefetch group g+1 (rows 1014-8g-j)
      int rw = NT - 10 - 8 * g - j;
      if (rw < 0) rw = 0;
      nqlo[j] = outb[rw * NC + l];
      nqhi[j] = outb[rw * NC + 64 + l];
      nplo[j] = potb[rw * NC + l];
      nphi[j] = potb[rw * NC + 64 + l];
    }
    #pragma unroll
    for (int j = 0; j < 8; ++j) {
      int t = NT - 1 - 8 * g - j;
      if (t >= 1) {
        // one-hot for row t
        outb[t * NC + l]      = (l == tag) ? 1.0f : 0.0f;
        outb[t * NC + 64 + l] = (64 + l == tag) ? 1.0f : 0.0f;
        // exact max of step t, no reduce needed:
        int Mlo = __builtin_amdgcn_readlane(__float_as_int(qlo_t), tag & 63);
        int Mhi = __builtin_amdgcn_readlane(__float_as_int(qhi_t), tag & 63);
        float M = __int_as_float((tag < 64) ? Mlo : Mhi);
        // bp: first p with alpha_{t-1}[p] + T[p][tag] == M
        f32x2 tt = tTp[tag * 64 + l];          // ds_read_b64
        float vlo = calo[j] + tt.x;
        float vhi = cahi[j] + tt.y;
        unsigned long long el = __ballot(vlo == M);
        unsigned long long eh = __ballot(vhi == M);
        tag = el ? (__ffsll((long long)el) - 1)
                 : (64 + __ffsll((long long)eh) - 1);
        qlo_t = cqlo[j];   // row t-1 becomes next step's row t
        qhi_t = cqhi[j];
      }
    }
    #pragma unroll
    for (int j = 0; j < 8; ++j) {
      cqlo[j] = nqlo[j]; cqhi[j] = nqhi[j];
      calo[j] = nqlo[j] + nplo[j];
      cahi[j] = nqhi[j] + nphi[j];
    }
  }
  outb[l]      = (l == tag) ? 1.0f : 0.0f;
  outb[64 + l] = (64 + l == tag) ? 1.0f : 0.0f;
}

// ---------------- launch ----------------

extern "C" void kernel_launch(void* const* d_in, const int* in_sizes, int n_in,
                              void* d_out, int out_size, void* d_ws, size_t ws_size,
                              hipStream_t stream) {
  const float* pot   = (const float*)d_in[0];
  const float* trans = (const float*)d_in[1];
  float* out = (float*)d_out;

  hipFuncSetAttribute((const void*)crf_bwd,
                      hipFuncAttributeMaxDynamicSharedMemorySize, NC * NC * 4);

  crf_fwd<<<NB, 512, 0, stream>>>(pot, trans, out);
  crf_bwd<<<NB, 256, NC * NC * 4, stream>>>(pot, trans, out);
}